// Round 6
// baseline (1708.984 us; speedup 1.0000x reference)
//
#include <hip/hip_runtime.h>
#include <math.h>

// ---- problem constants ----
#define B_SZ   4
#define LSEQ   1024
#define DMODEL 512
#define DINNER 1024
#define DSTATE 16
#define DCONV  4
#define DTRANK 32
#define NLAYER 8
#define NROWS  (B_SZ*LSEQ)      // 4096
#define CHUNK  32
#define NCHUNK (LSEQ/CHUNK)     // 32
#define KPAD   40               // 32 + 8 pad shorts: 80B row stride

__device__ __forceinline__ float sigmoid_(float x){ return 1.f/(1.f+__expf(-x)); }
// stable softplus, branch-free: max(v,0) + log(1+exp(-|v|))
__device__ __forceinline__ float softplus_(float v){
    return fmaxf(v,0.f) + __logf(1.f + __expf(-fabsf(v)));
}

typedef __attribute__((ext_vector_type(8))) short bf16x8;
typedef __attribute__((ext_vector_type(4))) short shortx4;
typedef __attribute__((ext_vector_type(4))) float f32x4;

__device__ __forceinline__ short f2bf(float f){
    unsigned int u = __float_as_uint(f);
    u = (u + 0x7FFFu + ((u >> 16) & 1u)) >> 16;     // RNE
    return (short)u;
}
__device__ __forceinline__ float bf2f(short s){
    unsigned int u = ((unsigned int)(unsigned short)s) << 16;
    return __uint_as_float(u);
}

// ============================================================================
// fp32 -> (hi, lo) bf16 split, elementwise (1024 floats per block)
// ============================================================================
__global__ __launch_bounds__(256) void split_k(
    const float* __restrict__ in, short* __restrict__ hi, short* __restrict__ lo)
{
    long i = ((long)blockIdx.x*256 + threadIdx.x)*4;
    float4 x = *reinterpret_cast<const float4*>(&in[i]);
    shortx4 h, l;
    h.x=f2bf(x.x); l.x=f2bf(x.x-bf2f(h.x));
    h.y=f2bf(x.y); l.y=f2bf(x.y-bf2f(h.y));
    h.z=f2bf(x.z); l.z=f2bf(x.z-bf2f(h.z));
    h.w=f2bf(x.w); l.w=f2bf(x.w-bf2f(h.w));
    *reinterpret_cast<shortx4*>(&hi[i]) = h;
    *reinterpret_cast<shortx4*>(&lo[i]) = l;
}

// combined per-layer weight split: blocks [0,1024) -> Wi (1M floats),
// blocks [1024,1536) -> Wo (512K floats)
__global__ __launch_bounds__(256) void split_w2(
    const float* __restrict__ wi, const float* __restrict__ wo,
    short* __restrict__ wih, short* __restrict__ wil,
    short* __restrict__ woh, short* __restrict__ wol)
{
    long bx = blockIdx.x;
    const float* src; short *ph, *pl; long base;
    if (bx < 1024) { src = wi; ph = wih; pl = wil; base = bx*1024; }
    else           { src = wo; ph = woh; pl = wol; base = (bx-1024)*1024; }
    long i = base + (long)threadIdx.x*4;
    float4 x = *reinterpret_cast<const float4*>(&src[i]);
    shortx4 h, l;
    h.x=f2bf(x.x); l.x=f2bf(x.x-bf2f(h.x));
    h.y=f2bf(x.y); l.y=f2bf(x.y-bf2f(h.y));
    h.z=f2bf(x.z); l.z=f2bf(x.z-bf2f(h.z));
    h.w=f2bf(x.w); l.w=f2bf(x.w-bf2f(h.w));
    *reinterpret_cast<shortx4*>(&ph[i]) = h;
    *reinterpret_cast<shortx4*>(&pl[i]) = l;
}

// ============================================================================
// MFMA GEMM on pre-split bf16 hi/lo operands, NT: C[m,n]=sum_k A[m,k]B[n,k].
// 4 waves (2x2); wave tile (BM/2)x(BN/2); BK=32; register-prefetch dbuf.
// acc += al*bh + ah*bl + ah*bh  (Markidis split, lo*lo dropped)
// EPI 0: fp32 store to C.  EPI 1: split bf16 store to Ch/Cl.
// ============================================================================
template<int BM,int BN,int EPI>
__global__ __launch_bounds__(256,4) void gemm_bs_nt(
    const short* __restrict__ Agh, const short* __restrict__ Agl, int lda,
    const short* __restrict__ Bgh, const short* __restrict__ Bgl, int ldb,
    float* __restrict__ C, int ldc,
    short* __restrict__ Ch, short* __restrict__ Cl, int K)
{
    constexpr int MREP = BM/32;
    constexpr int NREP = BN/32;
    constexpr int ACH  = BM/64;          // 16B chunks per thread per A array
    constexpr int BCH  = BN/64;
    __shared__ __align__(16) short Ahs[BM*KPAD], Als[BM*KPAD];
    __shared__ __align__(16) short Bhs[BN*KPAD], Bls[BN*KPAD];

    const int tid  = threadIdx.x;
    const int lane = tid & 63;
    const int wave = tid >> 6;
    const int wm = wave >> 1, wn = wave & 1;
    const int m0 = blockIdx.y * BM, n0 = blockIdx.x * BN;
    const int fr = lane & 15, fg = lane >> 4;

    int ar[ACH], ak[ACH];
#pragma unroll
    for (int j=0;j<ACH;j++){ int c = tid + j*256; ar[j]=c>>2; ak[j]=(c&3)*8; }
    int br[BCH], bk[BCH];
#pragma unroll
    for (int j=0;j<BCH;j++){ int c = tid + j*256; br[j]=c>>2; bk[j]=(c&3)*8; }

    f32x4 acc[MREP][NREP];
#pragma unroll
    for (int m=0;m<MREP;m++)
#pragma unroll
        for (int n=0;n<NREP;n++) acc[m][n] = (f32x4)0.f;

    bf16x8 rah[ACH], ral[ACH], rbh[BCH], rbl[BCH];

    auto load_tile = [&](int kt){
#pragma unroll
        for (int j=0;j<ACH;j++){
            long o = (long)(m0+ar[j])*lda + kt + ak[j];
            rah[j] = *reinterpret_cast<const bf16x8*>(&Agh[o]);
            ral[j] = *reinterpret_cast<const bf16x8*>(&Agl[o]);
        }
#pragma unroll
        for (int j=0;j<BCH;j++){
            long o = (long)(n0+br[j])*ldb + kt + bk[j];
            rbh[j] = *reinterpret_cast<const bf16x8*>(&Bgh[o]);
            rbl[j] = *reinterpret_cast<const bf16x8*>(&Bgl[o]);
        }
    };

    load_tile(0);
    const int NK = K >> 5;
    for (int s=0; s<NK; ++s){
#pragma unroll
        for (int j=0;j<ACH;j++){
            *reinterpret_cast<bf16x8*>(&Ahs[ar[j]*KPAD + ak[j]]) = rah[j];
            *reinterpret_cast<bf16x8*>(&Als[ar[j]*KPAD + ak[j]]) = ral[j];
        }
#pragma unroll
        for (int j=0;j<BCH;j++){
            *reinterpret_cast<bf16x8*>(&Bhs[br[j]*KPAD + bk[j]]) = rbh[j];
            *reinterpret_cast<bf16x8*>(&Bls[br[j]*KPAD + bk[j]]) = rbl[j];
        }
        __syncthreads();
        if (s+1 < NK) load_tile((s+1) << 5);   // in flight during MFMAs below

        bf16x8 bh[NREP], bl[NREP];
#pragma unroll
        for (int n=0;n<NREP;n++){
            int row = wn*(BN/2) + n*16 + fr;
            bh[n] = *reinterpret_cast<const bf16x8*>(&Bhs[row*KPAD + fg*8]);
            bl[n] = *reinterpret_cast<const bf16x8*>(&Bls[row*KPAD + fg*8]);
        }
#pragma unroll
        for (int m=0;m<MREP;m++){
            int row = wm*(BM/2) + m*16 + fr;
            bf16x8 ah = *reinterpret_cast<const bf16x8*>(&Ahs[row*KPAD + fg*8]);
            bf16x8 al = *reinterpret_cast<const bf16x8*>(&Als[row*KPAD + fg*8]);
#pragma unroll
            for (int n=0;n<NREP;n++){
                acc[m][n] = __builtin_amdgcn_mfma_f32_16x16x32_bf16(al, bh[n], acc[m][n],0,0,0);
                acc[m][n] = __builtin_amdgcn_mfma_f32_16x16x32_bf16(ah, bl[n], acc[m][n],0,0,0);
                acc[m][n] = __builtin_amdgcn_mfma_f32_16x16x32_bf16(ah, bh[n], acc[m][n],0,0,0);
            }
        }
        __syncthreads();
    }

    // epilogue: C[row][col], row=m0+wm*BM/2+m*16+fg*4+q, col=n0+wn*BN/2+n*16+fr
#pragma unroll
    for (int m=0;m<MREP;m++)
#pragma unroll
      for (int n=0;n<NREP;n++)
#pragma unroll
        for (int q=0;q<4;q++){
            int row = m0 + wm*(BM/2) + m*16 + fg*4 + q;
            int col = n0 + wn*(BN/2) + n*16 + fr;
            float v = acc[m][n][q];
            if (EPI==0) {
                C[(long)row*ldc + col] = v;
            } else {
                short h = f2bf(v);
                Ch[(long)row*ldc + col] = h;
                Cl[(long)row*ldc + col] = f2bf(v - bf2f(h));
            }
        }
}

// ============================================================================
// fp32 tiled GEMM — now only used for x_proj (split-K, atomic epilogue)
// ============================================================================
template<int BM,int BN,int BK,int TM,int TN,int EPI,bool SPLIT>
__global__ __launch_bounds__(256) void gemm_nt(
    const float* __restrict__ A, int lda,
    const float* __restrict__ Bmat, int ldb,
    float* __restrict__ C, int ldc,
    int M, int N, int K, int ksl,
    const float* __restrict__ bias)
{
    __shared__ float As[BK][BM+4];
    __shared__ float Bs[BK][BN+4];
    const int tid = threadIdx.x;
    const int tx = tid & 15, ty = tid >> 4;
    const int m0 = blockIdx.y * BM;
    const int n0 = blockIdx.x * BN;
    int k0 = 0, k1 = K;
    if (SPLIT) { k0 = blockIdx.z * ksl; k1 = k0 + ksl; }

    float acc[TM][TN];
#pragma unroll
    for (int i=0;i<TM;i++)
#pragma unroll
        for (int j=0;j<TN;j++) acc[i][j]=0.f;

    for (int kt=k0; kt<k1; kt+=BK) {
        constexpr int AV = BM*BK/4/256;
#pragma unroll
        for (int v=0; v<AV; ++v) {
            int idx = tid + v*256;
            int row = idx / (BK/4);
            int kq  = idx % (BK/4);
            float4 val = *reinterpret_cast<const float4*>(&A[(long)(m0+row)*lda + kt + kq*4]);
            As[kq*4+0][row]=val.x; As[kq*4+1][row]=val.y;
            As[kq*4+2][row]=val.z; As[kq*4+3][row]=val.w;
        }
        constexpr int BV = BN*BK/4/256;
#pragma unroll
        for (int v=0; v<BV; ++v) {
            int idx = tid + v*256;
            int row = idx / (BK/4);
            int kq  = idx % (BK/4);
            float4 val = *reinterpret_cast<const float4*>(&Bmat[(long)(n0+row)*ldb + kt + kq*4]);
            Bs[kq*4+0][row]=val.x; Bs[kq*4+1][row]=val.y;
            Bs[kq*4+2][row]=val.z; Bs[kq*4+3][row]=val.w;
        }
        __syncthreads();
#pragma unroll
        for (int k=0;k<BK;k++){
            float a[TM], b[TN];
#pragma unroll
            for (int i=0;i<TM;i+=4)
                *reinterpret_cast<float4*>(&a[i]) = *reinterpret_cast<const float4*>(&As[k][ty*TM+i]);
#pragma unroll
            for (int j=0;j<TN;j+=4)
                *reinterpret_cast<float4*>(&b[j]) = *reinterpret_cast<const float4*>(&Bs[k][tx*TN+j]);
#pragma unroll
            for (int i=0;i<TM;i++)
#pragma unroll
                for (int j=0;j<TN;j++) acc[i][j] = fmaf(a[i],b[j],acc[i][j]);
        }
        __syncthreads();
    }

#pragma unroll
    for (int i=0;i<TM;i++){
        int m = m0 + ty*TM + i;
        if (EPI==2) {
#pragma unroll
            for (int j=0;j<TN;j++) atomicAdd(&C[(long)m*ldc + n0 + tx*TN + j], acc[i][j]);
        } else {
#pragma unroll
            for (int j=0;j<TN;j+=4){
                int n = n0 + tx*TN + j;
                float4 o;
                float* po = &o.x;
#pragma unroll
                for (int q=0;q<4;q++){
                    float v = acc[i][j+q];
                    if (EPI==1) v = softplus_(v + bias[n+q]);
                    po[q] = v;
                }
                *reinterpret_cast<float4*>(&C[(long)m*ldc + n]) = o;
            }
        }
    }
}

// ============================================================================
// causal depthwise conv (k=4, left pad 3) + bias + silu; xz fp32 -> u fp32
// ============================================================================
__global__ __launch_bounds__(256) void conv_silu_k(
    const float* __restrict__ xz, const float* __restrict__ cw,
    const float* __restrict__ cb, float* __restrict__ u)
{
    int idx = blockIdx.x*256 + threadIdx.x;
    int d4  = idx & (DINNER/4 - 1);
    int row = idx >> 8;
    int t   = row & (LSEQ-1);

    float4 cbv = *reinterpret_cast<const float4*>(&cb[d4*4]);
    float acc[4] = {cbv.x, cbv.y, cbv.z, cbv.w};
    float4 cw0 = *reinterpret_cast<const float4*>(&cw[d4*16 + 0]);
    float4 cw1 = *reinterpret_cast<const float4*>(&cw[d4*16 + 4]);
    float4 cw2 = *reinterpret_cast<const float4*>(&cw[d4*16 + 8]);
    float4 cw3 = *reinterpret_cast<const float4*>(&cw[d4*16 +12]);
    const float* pw[4] = {&cw0.x, &cw1.x, &cw2.x, &cw3.x};

#pragma unroll
    for (int j=0;j<DCONV;j++){
        int tt = t - (DCONV-1) + j;
        if (tt < 0) continue;
        float4 xv = *reinterpret_cast<const float4*>(&xz[(long)(row-(DCONV-1)+j)*2*DINNER + d4*4]);
        acc[0] = fmaf(xv.x, pw[0][j], acc[0]);
        acc[1] = fmaf(xv.y, pw[1][j], acc[1]);
        acc[2] = fmaf(xv.z, pw[2][j], acc[2]);
        acc[3] = fmaf(xv.w, pw[3][j], acc[3]);
    }
    float4 o;
    o.x = acc[0]*sigmoid_(acc[0]);
    o.y = acc[1]*sigmoid_(acc[1]);
    o.z = acc[2]*sigmoid_(acc[2]);
    o.w = acc[3]*sigmoid_(acc[3]);
    *reinterpret_cast<float4*>(&u[(long)row*DINNER + d4*4]) = o;
}

// ============================================================================
// Chunked selective scan with FUSED delta:
// delta[row,d] = softplus(dot(dbc[row,0:32], Wdt[d,:]) + bdt[d]) computed
// on the fly (Wdt row in VGPRs, chunk's dt-rows staged in LDS, broadcast reads)
// ============================================================================
#define DTP 36   // LDS pitch for dt rows (float4-aligned, de-phased banks)

__global__ __launch_bounds__(256) void scan_phaseA(
    const float* __restrict__ u, const float* __restrict__ dbc,
    const float* __restrict__ Alog, const float* __restrict__ Wdt,
    const float* __restrict__ bdt,
    float* __restrict__ hst, float* __restrict__ sd)
{
    __shared__ float Bsh[CHUNK*DSTATE];
    __shared__ float Dtsh[CHUNK*DTP];
    int bx = blockIdx.x;
    int dblk = bx & 3;
    int c    = (bx>>2) & (NCHUNK-1);
    int b    = bx >> 7;
    int d    = dblk*256 + threadIdx.x;

    {   // stage B rows (512 floats) and dt rows (32x32 via float4)
        int i = threadIdx.x;
        int tr = i >> 3, c4 = (i & 7)*4;
        float4 dv = *reinterpret_cast<const float4*>(&dbc[(long)(b*LSEQ + c*CHUNK + tr)*64 + c4]);
        *reinterpret_cast<float4*>(&Dtsh[tr*DTP + c4]) = dv;
        for (int j = i; j < CHUNK*DSTATE; j += 256) {
            int r = j >> 4, s = j & 15;
            Bsh[j] = dbc[(long)(b*LSEQ + c*CHUNK + r)*64 + DTRANK + s];
        }
    }
    __syncthreads();

    float wdt[DTRANK];
#pragma unroll
    for (int q=0;q<DTRANK;q+=4)
        *reinterpret_cast<float4*>(&wdt[q]) = *reinterpret_cast<const float4*>(&Wdt[(long)d*DTRANK + q]);
    float bias = bdt[d];

    float As[DSTATE];
#pragma unroll
    for (int s=0;s<DSTATE;s++) As[s] = -__expf(Alog[d*DSTATE+s]);
    float h[DSTATE];
#pragma unroll
    for (int s=0;s<DSTATE;s++) h[s]=0.f;
    float sumd = 0.f;

    long baseU = (long)(b*LSEQ + c*CHUNK)*DINNER + d;
    for (int tt=0; tt<CHUNK; ++tt) {
        float v = bias;
#pragma unroll
        for (int r=0;r<DTRANK;r++) v = fmaf(Dtsh[tt*DTP + r], wdt[r], v);
        float dt = softplus_(v);
        float ut = u[baseU + (long)tt*DINNER];
        sumd += dt;
        float du = dt*ut;
#pragma unroll
        for (int s=0;s<DSTATE;s++)
            h[s] = fmaf(__expf(As[s]*dt), h[s], du*Bsh[tt*DSTATE+s]);
    }
    long ho = ((long)((b*NCHUNK + c)*DINNER) + d)*DSTATE;
#pragma unroll
    for (int s=0;s<DSTATE;s+=4)
        *reinterpret_cast<float4*>(&hst[ho+s]) = make_float4(h[s],h[s+1],h[s+2],h[s+3]);
    sd[(b*NCHUNK+c)*DINNER + d] = sumd;
}

__global__ __launch_bounds__(256) void scan_phaseB(
    const float* __restrict__ Alog, const float* __restrict__ sd,
    float* __restrict__ hst)
{
    int flat = blockIdx.x*256 + threadIdx.x;
    int s = flat & 15;
    int d = (flat >> 4) & (DINNER-1);
    int b = flat >> 14;
    float As = -__expf(Alog[d*DSTATE+s]);
    float H = 0.f;
    for (int c=0; c<NCHUNK; ++c) {
        long o = ((long)((b*NCHUNK+c)*DINNER)+d)*DSTATE + s;
        float hl  = hst[o];
        float sdc = sd[(b*NCHUNK+c)*DINNER + d];
        hst[o] = H;
        H = fmaf(__expf(As*sdc), H, hl);
    }
}

__global__ __launch_bounds__(256) void scan_phaseC(
    const float* __restrict__ xz, const float* __restrict__ u,
    const float* __restrict__ dbc, const float* __restrict__ Alog,
    const float* __restrict__ Wdt, const float* __restrict__ bdt,
    const float* __restrict__ hst, const float* __restrict__ Dsk,
    short* __restrict__ yh, short* __restrict__ yl)
{
    __shared__ float Bsh[CHUNK*DSTATE];
    __shared__ float Csh[CHUNK*DSTATE];
    __shared__ float Dtsh[CHUNK*DTP];
    int bx = blockIdx.x;
    int dblk = bx & 3;
    int c    = (bx>>2) & (NCHUNK-1);
    int b    = bx >> 7;
    int d    = dblk*256 + threadIdx.x;

    {
        int i = threadIdx.x;
        int tr = i >> 3, c4 = (i & 7)*4;
        float4 dv = *reinterpret_cast<const float4*>(&dbc[(long)(b*LSEQ + c*CHUNK + tr)*64 + c4]);
        *reinterpret_cast<float4*>(&Dtsh[tr*DTP + c4]) = dv;
        for (int j = i; j < CHUNK*DSTATE; j += 256) {
            int r = j >> 4, s = j & 15;
            long ro = (long)(b*LSEQ + c*CHUNK + r)*64;
            Bsh[j] = dbc[ro + DTRANK + s];
            Csh[j] = dbc[ro + DTRANK + DSTATE + s];
        }
    }
    __syncthreads();

    float wdt[DTRANK];
#pragma unroll
    for (int q=0;q<DTRANK;q+=4)
        *reinterpret_cast<float4*>(&wdt[q]) = *reinterpret_cast<const float4*>(&Wdt[(long)d*DTRANK + q]);
    float bias = bdt[d];

    float As[DSTATE];
#pragma unroll
    for (int s=0;s<DSTATE;s++) As[s] = -__expf(Alog[d*DSTATE+s]);
    float h[DSTATE];
    long ho = ((long)((b*NCHUNK + c)*DINNER) + d)*DSTATE;
#pragma unroll
    for (int s=0;s<DSTATE;s+=4){
        float4 hv = *reinterpret_cast<const float4*>(&hst[ho+s]);
        h[s]=hv.x; h[s+1]=hv.y; h[s+2]=hv.z; h[s+3]=hv.w;
    }
    float Dd = Dsk[d];

    long baseU = (long)(b*LSEQ + c*CHUNK)*DINNER + d;
    long baseZ = (long)(b*LSEQ + c*CHUNK)*2*DINNER + DINNER + d;
    for (int tt=0; tt<CHUNK; ++tt) {
        float v = bias;
#pragma unroll
        for (int r=0;r<DTRANK;r++) v = fmaf(Dtsh[tt*DTP + r], wdt[r], v);
        float dt = softplus_(v);
        float ut = u[baseU + (long)tt*DINNER];
        float du = dt*ut;
        float y = 0.f;
#pragma unroll
        for (int s=0;s<DSTATE;s++){
            h[s] = fmaf(__expf(As[s]*dt), h[s], du*Bsh[tt*DSTATE+s]);
            y = fmaf(h[s], Csh[tt*DSTATE+s], y);
        }
        y = fmaf(ut, Dd, y);
        float zv = xz[baseZ + (long)tt*2*DINNER];
        y *= zv * sigmoid_(zv);
        short hh = f2bf(y);
        yh[baseU + (long)tt*DINNER] = hh;
        yl[baseU + (long)tt*DINNER] = f2bf(y - bf2f(hh));
    }
}

// ============================================================================
extern "C" void kernel_launch(void* const* d_in, const int* in_sizes, int n_in,
                              void* d_out, int out_size, void* d_ws, size_t ws_size,
                              hipStream_t stream)
{
    const float* x_in = (const float*)d_in[0];
    const float* Wi   = (const float*)d_in[1];
    const float* cw   = (const float*)d_in[2];
    const float* cb   = (const float*)d_in[3];
    const float* Wx   = (const float*)d_in[4];
    const float* Wdt  = (const float*)d_in[5];
    const float* bdt  = (const float*)d_in[6];
    const float* Alog = (const float*)d_in[7];
    const float* Dsk  = (const float*)d_in[8];
    const float* Wo   = (const float*)d_in[9];
    float* out = (float*)d_out;

    // workspace layout: ~92 MB
    float* ws   = (float*)d_ws;
    float* xz   = ws;                        // 8388608 f
    float* u    = xz  + 8388608;             // 4194304 f
    float* dbc  = u   + 4194304;             // 262144 f
    float* hst  = dbc + 262144;              // 2097152 f
    float* sd   = hst + 2097152;             // 131072 f
    short* sp   = (short*)(sd + 131072);
    short* srch = sp;                        // 2097152 s (4096x512)
    short* srcl = srch + 2097152;
    short* wih  = srcl + 2097152;            // 1048576 s (2048x512)
    short* wil  = wih  + 1048576;
    short* woh  = wil  + 1048576;            // 524288 s (512x1024)
    short* wol  = woh  + 524288;
    short* yh   = wol  + 524288;             // 4194304 s (4096x1024)
    short* yl   = yh   + 4194304;

    // split layer-0 input
    split_k<<<NROWS*DMODEL/1024, 256, 0, stream>>>(x_in, srch, srcl);

    for (int l=0; l<NLAYER; ++l) {
        const float* Wi_l  = Wi  + (long)l*2*DINNER*DMODEL;
        const float* cw_l  = cw  + (long)l*DINNER*DCONV;
        const float* cb_l  = cb  + (long)l*DINNER;
        const float* Wx_l  = Wx  + (long)l*(DTRANK+2*DSTATE)*DINNER;
        const float* Wdt_l = Wdt + (long)l*DINNER*DTRANK;
        const float* bdt_l = bdt + (long)l*DINNER;
        const float* Al_l  = Alog+ (long)l*DINNER*DSTATE;
        const float* Dsk_l = Dsk + (long)l*DINNER;
        const float* Wo_l  = Wo  + (long)l*DMODEL*DINNER;

        // split Wi + Wo for this layer (one dispatch)
        split_w2<<<1536, 256, 0, stream>>>(Wi_l, Wo_l, wih, wil, woh, wol);

        // 1) xz = src @ Wi^T  (4096 x 2048, K=512)  128x64 tiles -> 1024 blocks
        gemm_bs_nt<128,64,0><<<dim3(2*DINNER/64, NROWS/128), 256, 0, stream>>>(
            srch, srcl, DMODEL, wih, wil, DMODEL, xz, 2*DINNER, nullptr, nullptr, DMODEL);

        // 2) u = silu(causal_dwconv(xin) + cb)
        conv_silu_k<<<NROWS*(DINNER/4)/256, 256, 0, stream>>>(xz, cw_l, cb_l, u);

        // 3) dbc = u @ Wx^T  (4096 x 64, K=1024) split-K=16 fp32 -> 1024 blocks
        hipMemsetAsync(dbc, 0, 262144*sizeof(float), stream);
        gemm_nt<64,64,16,4,4,2,true><<<dim3(1, NROWS/64, 16), 256, 0, stream>>>(
            u, DINNER, Wx_l, DINNER, dbc, 64, NROWS, 64, DINNER, DINNER/16, nullptr);

        // 4-6) chunked scan with fused delta; phaseC writes gated y split bf16
        scan_phaseA<<<B_SZ*NCHUNK*(DINNER/256), 256, 0, stream>>>(
            u, dbc, Al_l, Wdt_l, bdt_l, hst, sd);
        scan_phaseB<<<B_SZ*DINNER*DSTATE/256, 256, 0, stream>>>(Al_l, sd, hst);
        scan_phaseC<<<B_SZ*NCHUNK*(DINNER/256), 256, 0, stream>>>(
            xz, u, dbc, Al_l, Wdt_l, bdt_l, hst, Dsk_l, yh, yl);

        // 7) out = y @ Wo^T  (4096 x 512, K=1024)  64x64 tiles -> 512 blocks
        if (l == NLAYER-1) {
            gemm_bs_nt<64,64,0><<<dim3(DMODEL/64, NROWS/64), 256, 0, stream>>>(
                yh, yl, DINNER, woh, wol, DINNER, out, DMODEL, nullptr, nullptr, DINNER);
        } else {
            gemm_bs_nt<64,64,1><<<dim3(DMODEL/64, NROWS/64), 256, 0, stream>>>(
                yh, yl, DINNER, woh, wol, DINNER, nullptr, DMODEL, srch, srcl, DINNER);
        }
    }
}

// Round 9
// 1331.856 us; speedup vs baseline: 1.2832x; 1.2832x over previous
//
#include <hip/hip_runtime.h>
#include <math.h>

// ---- problem constants ----
#define B_SZ   4
#define LSEQ   1024
#define DMODEL 512
#define DINNER 1024
#define DSTATE 16
#define DCONV  4
#define DTRANK 32
#define NLAYER 8
#define NROWS  (B_SZ*LSEQ)      // 4096
#define CHUNK  32
#define NCHUNK (LSEQ/CHUNK)     // 32
#define KPAD   40               // 32 + 8 pad shorts: 80B row stride

__device__ __forceinline__ float sigmoid_(float x){ return 1.f/(1.f+__expf(-x)); }
// stable softplus, branch-free
__device__ __forceinline__ float softplus_(float v){
    return fmaxf(v,0.f) + __logf(1.f + __expf(-fabsf(v)));
}

typedef __attribute__((ext_vector_type(8))) short bf16x8;
typedef __attribute__((ext_vector_type(4))) short shortx4;
typedef __attribute__((ext_vector_type(4))) float f32x4;

__device__ __forceinline__ short f2bf(float f){
    unsigned int u = __float_as_uint(f);
    u = (u + 0x7FFFu + ((u >> 16) & 1u)) >> 16;     // RNE
    return (short)u;
}
__device__ __forceinline__ float bf2f(short s){
    unsigned int u = ((unsigned int)(unsigned short)s) << 16;
    return __uint_as_float(u);
}

// ============================================================================
// fp32 -> (hi, lo) bf16 split, elementwise (1024 floats per block)
// ============================================================================
__global__ __launch_bounds__(256) void split_k(
    const float* __restrict__ in, short* __restrict__ hi, short* __restrict__ lo)
{
    long i = ((long)blockIdx.x*256 + threadIdx.x)*4;
    float4 x = *reinterpret_cast<const float4*>(&in[i]);
    shortx4 h, l;
    h.x=f2bf(x.x); l.x=f2bf(x.x-bf2f(h.x));
    h.y=f2bf(x.y); l.y=f2bf(x.y-bf2f(h.y));
    h.z=f2bf(x.z); l.z=f2bf(x.z-bf2f(h.z));
    h.w=f2bf(x.w); l.w=f2bf(x.w-bf2f(h.w));
    *reinterpret_cast<shortx4*>(&hi[i]) = h;
    *reinterpret_cast<shortx4*>(&lo[i]) = l;
}

// per-layer weight split: [0,1024)->Wi, [1024,1536)->Wo, [1536,1600)->Wx
__global__ __launch_bounds__(256) void split_w3(
    const float* __restrict__ wi, const float* __restrict__ wo,
    const float* __restrict__ wx,
    short* __restrict__ wih, short* __restrict__ wil,
    short* __restrict__ woh, short* __restrict__ wol,
    short* __restrict__ wxh, short* __restrict__ wxl)
{
    long bx = blockIdx.x;
    const float* src; short *ph, *pl; long base;
    if      (bx < 1024) { src = wi; ph = wih; pl = wil; base = bx*1024; }
    else if (bx < 1536) { src = wo; ph = woh; pl = wol; base = (bx-1024)*1024; }
    else                { src = wx; ph = wxh; pl = wxl; base = (bx-1536)*1024; }
    long i = base + (long)threadIdx.x*4;
    float4 x = *reinterpret_cast<const float4*>(&src[i]);
    shortx4 h, l;
    h.x=f2bf(x.x); l.x=f2bf(x.x-bf2f(h.x));
    h.y=f2bf(x.y); l.y=f2bf(x.y-bf2f(h.y));
    h.z=f2bf(x.z); l.z=f2bf(x.z-bf2f(h.z));
    h.w=f2bf(x.w); l.w=f2bf(x.w-bf2f(h.w));
    *reinterpret_cast<shortx4*>(&ph[i]) = h;
    *reinterpret_cast<shortx4*>(&pl[i]) = l;
}

// ============================================================================
// MFMA GEMM on pre-split bf16 hi/lo operands, NT: C[m,n]=sum_k A[m,k]B[n,k].
// 4 waves (2x2); wave tile (BM/2)x(BN/2); BK=32; register-prefetch dbuf.
// acc += al*bh + ah*bl + ah*bh  (Markidis split, lo*lo dropped)
// EPI 0: fp32 store. EPI 1: split bf16 store. EPI 2: fp32 partial store at
//        slice offset blockIdx.z (non-atomic split-K).
// ============================================================================
template<int BM,int BN,int EPI,bool SPLITK>
__global__ __launch_bounds__(256,4) void gemm_bs_nt(
    const short* __restrict__ Agh, const short* __restrict__ Agl, int lda,
    const short* __restrict__ Bgh, const short* __restrict__ Bgl, int ldb,
    float* __restrict__ C, int ldc,
    short* __restrict__ Ch, short* __restrict__ Cl, int K, int ksl)
{
    constexpr int MREP = BM/32;
    constexpr int NREP = BN/32;
    constexpr int ACH  = BM/64;          // 16B chunks per thread per A array
    constexpr int BCH  = BN/64;
    __shared__ __align__(16) short Ahs[BM*KPAD], Als[BM*KPAD];
    __shared__ __align__(16) short Bhs[BN*KPAD], Bls[BN*KPAD];

    const int tid  = threadIdx.x;
    const int lane = tid & 63;
    const int wave = tid >> 6;
    const int wm = wave >> 1, wn = wave & 1;
    const int m0 = blockIdx.y * BM, n0 = blockIdx.x * BN;
    const int fr = lane & 15, fg = lane >> 4;
    const int k0 = SPLITK ? blockIdx.z * ksl : 0;

    int ar[ACH], ak[ACH];
#pragma unroll
    for (int j=0;j<ACH;j++){ int c = tid + j*256; ar[j]=c>>2; ak[j]=(c&3)*8; }
    int br[BCH], bk[BCH];
#pragma unroll
    for (int j=0;j<BCH;j++){ int c = tid + j*256; br[j]=c>>2; bk[j]=(c&3)*8; }

    f32x4 acc[MREP][NREP];
#pragma unroll
    for (int m=0;m<MREP;m++)
#pragma unroll
        for (int n=0;n<NREP;n++) acc[m][n] = (f32x4)0.f;

    bf16x8 rah[ACH], ral[ACH], rbh[BCH], rbl[BCH];

    auto load_tile = [&](int kt){
#pragma unroll
        for (int j=0;j<ACH;j++){
            long o = (long)(m0+ar[j])*lda + kt + ak[j];
            rah[j] = *reinterpret_cast<const bf16x8*>(&Agh[o]);
            ral[j] = *reinterpret_cast<const bf16x8*>(&Agl[o]);
        }
#pragma unroll
        for (int j=0;j<BCH;j++){
            long o = (long)(n0+br[j])*ldb + kt + bk[j];
            rbh[j] = *reinterpret_cast<const bf16x8*>(&Bgh[o]);
            rbl[j] = *reinterpret_cast<const bf16x8*>(&Bgl[o]);
        }
    };

    load_tile(k0);
    const int NK = (SPLITK ? ksl : K) >> 5;
    for (int s=0; s<NK; ++s){
#pragma unroll
        for (int j=0;j<ACH;j++){
            *reinterpret_cast<bf16x8*>(&Ahs[ar[j]*KPAD + ak[j]]) = rah[j];
            *reinterpret_cast<bf16x8*>(&Als[ar[j]*KPAD + ak[j]]) = ral[j];
        }
#pragma unroll
        for (int j=0;j<BCH;j++){
            *reinterpret_cast<bf16x8*>(&Bhs[br[j]*KPAD + bk[j]]) = rbh[j];
            *reinterpret_cast<bf16x8*>(&Bls[br[j]*KPAD + bk[j]]) = rbl[j];
        }
        __syncthreads();
        if (s+1 < NK) load_tile(k0 + ((s+1) << 5));   // in flight during MFMAs

        bf16x8 bh[NREP], bl[NREP];
#pragma unroll
        for (int n=0;n<NREP;n++){
            int row = wn*(BN/2) + n*16 + fr;
            bh[n] = *reinterpret_cast<const bf16x8*>(&Bhs[row*KPAD + fg*8]);
            bl[n] = *reinterpret_cast<const bf16x8*>(&Bls[row*KPAD + fg*8]);
        }
#pragma unroll
        for (int m=0;m<MREP;m++){
            int row = wm*(BM/2) + m*16 + fr;
            bf16x8 ah = *reinterpret_cast<const bf16x8*>(&Ahs[row*KPAD + fg*8]);
            bf16x8 al = *reinterpret_cast<const bf16x8*>(&Als[row*KPAD + fg*8]);
#pragma unroll
            for (int n=0;n<NREP;n++){
                acc[m][n] = __builtin_amdgcn_mfma_f32_16x16x32_bf16(al, bh[n], acc[m][n],0,0,0);
                acc[m][n] = __builtin_amdgcn_mfma_f32_16x16x32_bf16(ah, bl[n], acc[m][n],0,0,0);
                acc[m][n] = __builtin_amdgcn_mfma_f32_16x16x32_bf16(ah, bh[n], acc[m][n],0,0,0);
            }
        }
        __syncthreads();
    }

    // epilogue: row=m0+wm*BM/2+m*16+fg*4+q, col=n0+wn*BN/2+n*16+fr
#pragma unroll
    for (int m=0;m<MREP;m++)
#pragma unroll
      for (int n=0;n<NREP;n++)
#pragma unroll
        for (int q=0;q<4;q++){
            int row = m0 + wm*(BM/2) + m*16 + fg*4 + q;
            int col = n0 + wn*(BN/2) + n*16 + fr;
            float v = acc[m][n][q];
            if (EPI==0) {
                C[(long)row*ldc + col] = v;
            } else if (EPI==1) {
                short h = f2bf(v);
                Ch[(long)row*ldc + col] = h;
                Cl[(long)row*ldc + col] = f2bf(v - bf2f(h));
            } else {
                C[((long)blockIdx.z*NROWS + row)*ldc + col] = v;
            }
        }
}

// ============================================================================
// split-K partial reduce: dbc = sum over 8 slices (float4 per thread)
// ============================================================================
__global__ __launch_bounds__(256) void reduce_dbc(
    const float* __restrict__ part, float* __restrict__ dbc)
{
    long i = ((long)blockIdx.x*256 + threadIdx.x)*4;
    float4 a = *reinterpret_cast<const float4*>(&part[i]);
#pragma unroll
    for (int s=1;s<8;s++){
        float4 b = *reinterpret_cast<const float4*>(&part[(long)s*(NROWS*64) + i]);
        a.x+=b.x; a.y+=b.y; a.z+=b.z; a.w+=b.w;
    }
    *reinterpret_cast<float4*>(&dbc[i]) = a;
}

// ============================================================================
// causal depthwise conv (k=4) + bias + silu; writes u fp32 AND split bf16
// ============================================================================
__global__ __launch_bounds__(256) void conv_silu_k(
    const float* __restrict__ xz, const float* __restrict__ cw,
    const float* __restrict__ cb, float* __restrict__ u,
    short* __restrict__ uh, short* __restrict__ ul)
{
    int idx = blockIdx.x*256 + threadIdx.x;
    int d4  = idx & (DINNER/4 - 1);
    int row = idx >> 8;
    int t   = row & (LSEQ-1);

    float4 cbv = *reinterpret_cast<const float4*>(&cb[d4*4]);
    float acc[4] = {cbv.x, cbv.y, cbv.z, cbv.w};
    float4 cw0 = *reinterpret_cast<const float4*>(&cw[d4*16 + 0]);
    float4 cw1 = *reinterpret_cast<const float4*>(&cw[d4*16 + 4]);
    float4 cw2 = *reinterpret_cast<const float4*>(&cw[d4*16 + 8]);
    float4 cw3 = *reinterpret_cast<const float4*>(&cw[d4*16 +12]);
    const float* pw[4] = {&cw0.x, &cw1.x, &cw2.x, &cw3.x};

#pragma unroll
    for (int j=0;j<DCONV;j++){
        int tt = t - (DCONV-1) + j;
        if (tt < 0) continue;
        float4 xv = *reinterpret_cast<const float4*>(&xz[(long)(row-(DCONV-1)+j)*2*DINNER + d4*4]);
        acc[0] = fmaf(xv.x, pw[0][j], acc[0]);
        acc[1] = fmaf(xv.y, pw[1][j], acc[1]);
        acc[2] = fmaf(xv.z, pw[2][j], acc[2]);
        acc[3] = fmaf(xv.w, pw[3][j], acc[3]);
    }
    float4 o;
    o.x = acc[0]*sigmoid_(acc[0]);
    o.y = acc[1]*sigmoid_(acc[1]);
    o.z = acc[2]*sigmoid_(acc[2]);
    o.w = acc[3]*sigmoid_(acc[3]);
    long base = (long)row*DINNER + d4*4;
    *reinterpret_cast<float4*>(&u[base]) = o;
    shortx4 h, l;
    h.x=f2bf(o.x); l.x=f2bf(o.x-bf2f(h.x));
    h.y=f2bf(o.y); l.y=f2bf(o.y-bf2f(h.y));
    h.z=f2bf(o.z); l.z=f2bf(o.z-bf2f(h.z));
    h.w=f2bf(o.w); l.w=f2bf(o.w-bf2f(h.w));
    *reinterpret_cast<shortx4*>(&uh[base]) = h;
    *reinterpret_cast<shortx4*>(&ul[base]) = l;
}

// ============================================================================
// Chunked selective scan with fused delta (dt GEMV per thread from LDS rows)
// ============================================================================
#define DTP 36

__global__ __launch_bounds__(256) void scan_phaseA(
    const float* __restrict__ u, const float* __restrict__ dbc,
    const float* __restrict__ Alog, const float* __restrict__ Wdt,
    const float* __restrict__ bdt,
    float* __restrict__ hst, float* __restrict__ sd)
{
    __shared__ float Bsh[CHUNK*DSTATE];
    __shared__ float Dtsh[CHUNK*DTP];
    int bx = blockIdx.x;
    int dblk = bx & 3;
    int c    = (bx>>2) & (NCHUNK-1);
    int b    = bx >> 7;
    int d    = dblk*256 + threadIdx.x;

    {
        int i = threadIdx.x;
        int tr = i >> 3, c4 = (i & 7)*4;
        float4 dv = *reinterpret_cast<const float4*>(&dbc[(long)(b*LSEQ + c*CHUNK + tr)*64 + c4]);
        *reinterpret_cast<float4*>(&Dtsh[tr*DTP + c4]) = dv;
        for (int j = i; j < CHUNK*DSTATE; j += 256) {
            int r = j >> 4, s = j & 15;
            Bsh[j] = dbc[(long)(b*LSEQ + c*CHUNK + r)*64 + DTRANK + s];
        }
    }
    __syncthreads();

    float wdt[DTRANK];
#pragma unroll
    for (int q=0;q<DTRANK;q+=4)
        *reinterpret_cast<float4*>(&wdt[q]) = *reinterpret_cast<const float4*>(&Wdt[(long)d*DTRANK + q]);
    float bias = bdt[d];

    float As[DSTATE];
#pragma unroll
    for (int s=0;s<DSTATE;s++) As[s] = -__expf(Alog[d*DSTATE+s]);
    float h[DSTATE];
#pragma unroll
    for (int s=0;s<DSTATE;s++) h[s]=0.f;
    float sumd = 0.f;

    long baseU = (long)(b*LSEQ + c*CHUNK)*DINNER + d;
    for (int tt=0; tt<CHUNK; ++tt) {
        float v = bias;
#pragma unroll
        for (int r=0;r<DTRANK;r++) v = fmaf(Dtsh[tt*DTP + r], wdt[r], v);
        float dt = softplus_(v);
        float ut = u[baseU + (long)tt*DINNER];
        sumd += dt;
        float du = dt*ut;
#pragma unroll
        for (int s=0;s<DSTATE;s++)
            h[s] = fmaf(__expf(As[s]*dt), h[s], du*Bsh[tt*DSTATE+s]);
    }
    long ho = ((long)((b*NCHUNK + c)*DINNER) + d)*DSTATE;
#pragma unroll
    for (int s=0;s<DSTATE;s+=4)
        *reinterpret_cast<float4*>(&hst[ho+s]) = make_float4(h[s],h[s+1],h[s+2],h[s+3]);
    sd[(b*NCHUNK+c)*DINNER + d] = sumd;
}

__global__ __launch_bounds__(256) void scan_phaseB(
    const float* __restrict__ Alog, const float* __restrict__ sd,
    float* __restrict__ hst)
{
    int flat = blockIdx.x*256 + threadIdx.x;
    int s = flat & 15;
    int d = (flat >> 4) & (DINNER-1);
    int b = flat >> 14;
    float As = -__expf(Alog[d*DSTATE+s]);
    float H = 0.f;
    for (int c=0; c<NCHUNK; ++c) {
        long o = ((long)((b*NCHUNK+c)*DINNER)+d)*DSTATE + s;
        float hl  = hst[o];
        float sdc = sd[(b*NCHUNK+c)*DINNER + d];
        hst[o] = H;
        H = fmaf(__expf(As*sdc), H, hl);
    }
}

__global__ __launch_bounds__(256) void scan_phaseC(
    const float* __restrict__ xz, const float* __restrict__ u,
    const float* __restrict__ dbc, const float* __restrict__ Alog,
    const float* __restrict__ Wdt, const float* __restrict__ bdt,
    const float* __restrict__ hst, const float* __restrict__ Dsk,
    short* __restrict__ yh, short* __restrict__ yl)
{
    __shared__ float Bsh[CHUNK*DSTATE];
    __shared__ float Csh[CHUNK*DSTATE];
    __shared__ float Dtsh[CHUNK*DTP];
    int bx = blockIdx.x;
    int dblk = bx & 3;
    int c    = (bx>>2) & (NCHUNK-1);
    int b    = bx >> 7;
    int d    = dblk*256 + threadIdx.x;

    {
        int i = threadIdx.x;
        int tr = i >> 3, c4 = (i & 7)*4;
        float4 dv = *reinterpret_cast<const float4*>(&dbc[(long)(b*LSEQ + c*CHUNK + tr)*64 + c4]);
        *reinterpret_cast<float4*>(&Dtsh[tr*DTP + c4]) = dv;
        for (int j = i; j < CHUNK*DSTATE; j += 256) {
            int r = j >> 4, s = j & 15;
            long ro = (long)(b*LSEQ + c*CHUNK + r)*64;
            Bsh[j] = dbc[ro + DTRANK + s];
            Csh[j] = dbc[ro + DTRANK + DSTATE + s];
        }
    }
    __syncthreads();

    float wdt[DTRANK];
#pragma unroll
    for (int q=0;q<DTRANK;q+=4)
        *reinterpret_cast<float4*>(&wdt[q]) = *reinterpret_cast<const float4*>(&Wdt[(long)d*DTRANK + q]);
    float bias = bdt[d];

    float As[DSTATE];
#pragma unroll
    for (int s=0;s<DSTATE;s++) As[s] = -__expf(Alog[d*DSTATE+s]);
    float h[DSTATE];
    long ho = ((long)((b*NCHUNK + c)*DINNER) + d)*DSTATE;
#pragma unroll
    for (int s=0;s<DSTATE;s+=4){
        float4 hv = *reinterpret_cast<const float4*>(&hst[ho+s]);
        h[s]=hv.x; h[s+1]=hv.y; h[s+2]=hv.z; h[s+3]=hv.w;
    }
    float Dd = Dsk[d];

    long baseU = (long)(b*LSEQ + c*CHUNK)*DINNER + d;
    long baseZ = (long)(b*LSEQ + c*CHUNK)*2*DINNER + DINNER + d;
    for (int tt=0; tt<CHUNK; ++tt) {
        float v = bias;
#pragma unroll
        for (int r=0;r<DTRANK;r++) v = fmaf(Dtsh[tt*DTP + r], wdt[r], v);
        float dt = softplus_(v);
        float ut = u[baseU + (long)tt*DINNER];
        float du = dt*ut;
        float y = 0.f;
#pragma unroll
        for (int s=0;s<DSTATE;s++){
            h[s] = fmaf(__expf(As[s]*dt), h[s], du*Bsh[tt*DSTATE+s]);
            y = fmaf(h[s], Csh[tt*DSTATE+s], y);
        }
        y = fmaf(ut, Dd, y);
        float zv = xz[baseZ + (long)tt*2*DINNER];
        y *= zv * sigmoid_(zv);
        short hh = f2bf(y);
        yh[baseU + (long)tt*DINNER] = hh;
        yl[baseU + (long)tt*DINNER] = f2bf(y - bf2f(hh));
    }
}

// ============================================================================
extern "C" void kernel_launch(void* const* d_in, const int* in_sizes, int n_in,
                              void* d_out, int out_size, void* d_ws, size_t ws_size,
                              hipStream_t stream)
{
    const float* x_in = (const float*)d_in[0];
    const float* Wi   = (const float*)d_in[1];
    const float* cw   = (const float*)d_in[2];
    const float* cb   = (const float*)d_in[3];
    const float* Wx   = (const float*)d_in[4];
    const float* Wdt  = (const float*)d_in[5];
    const float* bdt  = (const float*)d_in[6];
    const float* Alog = (const float*)d_in[7];
    const float* Dsk  = (const float*)d_in[8];
    const float* Wo   = (const float*)d_in[9];
    float* out = (float*)d_out;

    // workspace layout (~92 MB). Overlays (sequential-stream lifetimes):
    //   partials == hst   (x_proj partials dead before scanA writes hst)
    //   uh/ul   == yh/yl  (uh dead after x_proj; scanC then writes yh)
    float* ws   = (float*)d_ws;
    float* xz   = ws;                        // 8388608 f
    float* u    = xz  + 8388608;             // 4194304 f
    float* dbc  = u   + 4194304;             // 262144 f
    float* hst  = dbc + 262144;              // 2097152 f (= 8 x 262144 partials)
    float* sd   = hst + 2097152;             // 131072 f
    short* sp   = (short*)(sd + 131072);
    short* srch = sp;                        // 2097152 s (4096x512)
    short* srcl = srch + 2097152;
    short* wih  = srcl + 2097152;            // 1048576 s
    short* wil  = wih  + 1048576;
    short* woh  = wil  + 1048576;            // 524288 s
    short* wol  = woh  + 524288;
    short* wxh  = wol  + 524288;             // 65536 s (64x1024)
    short* wxl  = wxh  + 65536;
    short* yh   = wxl  + 65536;              // 4194304 s (4096x1024), = uh
    short* yl   = yh   + 4194304;            //                        = ul

    // split layer-0 input
    split_k<<<NROWS*DMODEL/1024, 256, 0, stream>>>(x_in, srch, srcl);

    for (int l=0; l<NLAYER; ++l) {
        const float* Wi_l  = Wi  + (long)l*2*DINNER*DMODEL;
        const float* cw_l  = cw  + (long)l*DINNER*DCONV;
        const float* cb_l  = cb  + (long)l*DINNER;
        const float* Wx_l  = Wx  + (long)l*(DTRANK+2*DSTATE)*DINNER;
        const float* Wdt_l = Wdt + (long)l*DINNER*DTRANK;
        const float* bdt_l = bdt + (long)l*DINNER;
        const float* Al_l  = Alog+ (long)l*DINNER*DSTATE;
        const float* Dsk_l = Dsk + (long)l*DINNER;
        const float* Wo_l  = Wo  + (long)l*DMODEL*DINNER;

        // split Wi + Wo + Wx for this layer (one dispatch)
        split_w3<<<1600, 256, 0, stream>>>(Wi_l, Wo_l, Wx_l, wih, wil, woh, wol, wxh, wxl);

        // 1) xz = src @ Wi^T  (4096 x 2048, K=512)  128x64 tiles -> 1024 blocks
        gemm_bs_nt<128,64,0,false><<<dim3(2*DINNER/64, NROWS/128), 256, 0, stream>>>(
            srch, srcl, DMODEL, wih, wil, DMODEL, xz, 2*DINNER, nullptr, nullptr, DMODEL, DMODEL);

        // 2) u = silu(causal_dwconv(xin) + cb); also split bf16 -> uh/ul (=yh/yl)
        conv_silu_k<<<NROWS*(DINNER/4)/256, 256, 0, stream>>>(xz, cw_l, cb_l, u, yh, yl);

        // 3) dbc partials = u @ Wx^T (4096x64, K=1024) MFMA split-K=8 -> 256 blocks
        gemm_bs_nt<128,64,2,true><<<dim3(1, NROWS/128, 8), 256, 0, stream>>>(
            yh, yl, DINNER, wxh, wxl, DINNER, hst, 64, nullptr, nullptr, DINNER, DINNER/8);
        reduce_dbc<<<NROWS*64/1024, 256, 0, stream>>>(hst, dbc);

        // 4-6) chunked scan with fused delta; phaseC writes gated y split bf16
        scan_phaseA<<<B_SZ*NCHUNK*(DINNER/256), 256, 0, stream>>>(
            u, dbc, Al_l, Wdt_l, bdt_l, hst, sd);
        scan_phaseB<<<B_SZ*DINNER*DSTATE/256, 256, 0, stream>>>(Al_l, sd, hst);
        scan_phaseC<<<B_SZ*NCHUNK*(DINNER/256), 256, 0, stream>>>(
            xz, u, dbc, Al_l, Wdt_l, bdt_l, hst, Dsk_l, yh, yl);

        // 7) out = y @ Wo^T  (4096 x 512, K=1024)  64x64 tiles -> 512 blocks
        if (l == NLAYER-1) {
            gemm_bs_nt<64,64,0,false><<<dim3(DMODEL/64, NROWS/64), 256, 0, stream>>>(
                yh, yl, DINNER, woh, wol, DINNER, out, DMODEL, nullptr, nullptr, DINNER, DINNER);
        } else {
            gemm_bs_nt<64,64,1,false><<<dim3(DMODEL/64, NROWS/64), 256, 0, stream>>>(
                yh, yl, DINNER, woh, wol, DINNER, nullptr, DMODEL, srch, srcl, DINNER, DINNER);
        }
    }
}

// Round 10
// 1325.662 us; speedup vs baseline: 1.2892x; 1.0047x over previous
//
#include <hip/hip_runtime.h>
#include <math.h>

// ---- problem constants ----
#define B_SZ   4
#define LSEQ   1024
#define DMODEL 512
#define DINNER 1024
#define DSTATE 16
#define DCONV  4
#define DTRANK 32
#define NLAYER 8
#define NROWS  (B_SZ*LSEQ)      // 4096
#define CHUNK  32
#define NCHUNK (LSEQ/CHUNK)     // 32
#define KPAD   40               // 32 + 8 pad shorts: 80B row stride
#define WSTRIDE 3276800L        // shorts per layer of split weights

__device__ __forceinline__ float sigmoid_(float x){ return 1.f/(1.f+__expf(-x)); }
__device__ __forceinline__ float softplus_(float v){
    return fmaxf(v,0.f) + __logf(1.f + __expf(-fabsf(v)));
}

typedef __attribute__((ext_vector_type(8))) short bf16x8;
typedef __attribute__((ext_vector_type(4))) short shortx4;
typedef __attribute__((ext_vector_type(4))) float f32x4;

__device__ __forceinline__ short f2bf(float f){
    unsigned int u = __float_as_uint(f);
    u = (u + 0x7FFFu + ((u >> 16) & 1u)) >> 16;     // RNE
    return (short)u;
}
__device__ __forceinline__ float bf2f(short s){
    unsigned int u = ((unsigned int)(unsigned short)s) << 16;
    return __uint_as_float(u);
}

// ============================================================================
// fp32 -> (hi, lo) bf16 split, elementwise (1024 floats per block)
// ============================================================================
__global__ __launch_bounds__(256) void split_k(
    const float* __restrict__ in, short* __restrict__ hi, short* __restrict__ lo)
{
    long i = ((long)blockIdx.x*256 + threadIdx.x)*4;
    float4 x = *reinterpret_cast<const float4*>(&in[i]);
    shortx4 h, l;
    h.x=f2bf(x.x); l.x=f2bf(x.x-bf2f(h.x));
    h.y=f2bf(x.y); l.y=f2bf(x.y-bf2f(h.y));
    h.z=f2bf(x.z); l.z=f2bf(x.z-bf2f(h.z));
    h.w=f2bf(x.w); l.w=f2bf(x.w-bf2f(h.w));
    *reinterpret_cast<shortx4*>(&hi[i]) = h;
    *reinterpret_cast<shortx4*>(&lo[i]) = l;
}

// ============================================================================
// ALL layers' weight split in one dispatch. Per layer 1600 blocks:
// [0,1024)->Wi (1048576 f), [1024,1536)->Wo (524288 f), [1536,1600)->Wx (65536 f)
// Layer region (shorts): wih@0, wil@1048576, woh@2097152, wol@2621440,
//                        wxh@3145728, wxl@3211264   (WSTRIDE total)
// ============================================================================
__global__ __launch_bounds__(256) void split_w_all(
    const float* __restrict__ wi, const float* __restrict__ wo,
    const float* __restrict__ wx, short* __restrict__ wsp)
{
    int bx = blockIdx.x;
    int l  = bx / 1600, r = bx % 1600;
    short* lw = wsp + (long)l*WSTRIDE;
    const float* src; short *ph, *pl; long base;
    if      (r < 1024) { src = wi + (long)l*1048576; base = (long)r*1024;        ph = lw;         pl = lw+1048576; }
    else if (r < 1536) { src = wo + (long)l*524288;  base = (long)(r-1024)*1024; ph = lw+2097152; pl = lw+2621440; }
    else               { src = wx + (long)l*65536;   base = (long)(r-1536)*1024; ph = lw+3145728; pl = lw+3211264; }
    long i = base + (long)threadIdx.x*4;
    float4 x = *reinterpret_cast<const float4*>(&src[i]);
    shortx4 h, l4;
    h.x=f2bf(x.x); l4.x=f2bf(x.x-bf2f(h.x));
    h.y=f2bf(x.y); l4.y=f2bf(x.y-bf2f(h.y));
    h.z=f2bf(x.z); l4.z=f2bf(x.z-bf2f(h.z));
    h.w=f2bf(x.w); l4.w=f2bf(x.w-bf2f(h.w));
    *reinterpret_cast<shortx4*>(&ph[i]) = h;
    *reinterpret_cast<shortx4*>(&pl[i]) = l4;
}

// ============================================================================
// MFMA GEMM on pre-split bf16 hi/lo operands, NT: C[m,n]=sum_k A[m,k]B[n,k].
// 4 waves (2x2); wave tile (BM/2)x(BN/2); BK=32; register-prefetch dbuf.
// acc += al*bh + ah*bl + ah*bh  (Markidis split, lo*lo dropped)
// EPI 0: fp32 store. EPI 1: split bf16 store. EPI 2: fp32 partial store at
//        slice offset blockIdx.z (non-atomic split-K).
// MINW: min waves/EU for launch_bounds (2 for the 128x128 tile -> <=256 VGPR).
// ============================================================================
template<int BM,int BN,int EPI,bool SPLITK,int MINW>
__global__ __launch_bounds__(256,MINW) void gemm_bs_nt(
    const short* __restrict__ Agh, const short* __restrict__ Agl, int lda,
    const short* __restrict__ Bgh, const short* __restrict__ Bgl, int ldb,
    float* __restrict__ C, int ldc,
    short* __restrict__ Ch, short* __restrict__ Cl, int K, int ksl)
{
    constexpr int MREP = BM/32;
    constexpr int NREP = BN/32;
    constexpr int ACH  = BM/64;          // 16B chunks per thread per A array
    constexpr int BCH  = BN/64;
    __shared__ __align__(16) short Ahs[BM*KPAD], Als[BM*KPAD];
    __shared__ __align__(16) short Bhs[BN*KPAD], Bls[BN*KPAD];

    const int tid  = threadIdx.x;
    const int lane = tid & 63;
    const int wave = tid >> 6;
    const int wm = wave >> 1, wn = wave & 1;
    const int m0 = blockIdx.y * BM, n0 = blockIdx.x * BN;
    const int fr = lane & 15, fg = lane >> 4;
    const int k0 = SPLITK ? blockIdx.z * ksl : 0;

    int ar[ACH], ak[ACH];
#pragma unroll
    for (int j=0;j<ACH;j++){ int c = tid + j*256; ar[j]=c>>2; ak[j]=(c&3)*8; }
    int br[BCH], bk[BCH];
#pragma unroll
    for (int j=0;j<BCH;j++){ int c = tid + j*256; br[j]=c>>2; bk[j]=(c&3)*8; }

    f32x4 acc[MREP][NREP];
#pragma unroll
    for (int m=0;m<MREP;m++)
#pragma unroll
        for (int n=0;n<NREP;n++) acc[m][n] = (f32x4)0.f;

    bf16x8 rah[ACH], ral[ACH], rbh[BCH], rbl[BCH];

    auto load_tile = [&](int kt){
#pragma unroll
        for (int j=0;j<ACH;j++){
            long o = (long)(m0+ar[j])*lda + kt + ak[j];
            rah[j] = *reinterpret_cast<const bf16x8*>(&Agh[o]);
            ral[j] = *reinterpret_cast<const bf16x8*>(&Agl[o]);
        }
#pragma unroll
        for (int j=0;j<BCH;j++){
            long o = (long)(n0+br[j])*ldb + kt + bk[j];
            rbh[j] = *reinterpret_cast<const bf16x8*>(&Bgh[o]);
            rbl[j] = *reinterpret_cast<const bf16x8*>(&Bgl[o]);
        }
    };

    load_tile(k0);
    const int NK = (SPLITK ? ksl : K) >> 5;
    for (int s=0; s<NK; ++s){
#pragma unroll
        for (int j=0;j<ACH;j++){
            *reinterpret_cast<bf16x8*>(&Ahs[ar[j]*KPAD + ak[j]]) = rah[j];
            *reinterpret_cast<bf16x8*>(&Als[ar[j]*KPAD + ak[j]]) = ral[j];
        }
#pragma unroll
        for (int j=0;j<BCH;j++){
            *reinterpret_cast<bf16x8*>(&Bhs[br[j]*KPAD + bk[j]]) = rbh[j];
            *reinterpret_cast<bf16x8*>(&Bls[br[j]*KPAD + bk[j]]) = rbl[j];
        }
        __syncthreads();
        if (s+1 < NK) load_tile(k0 + ((s+1) << 5));   // in flight during MFMAs

        bf16x8 bh[NREP], bl[NREP];
#pragma unroll
        for (int n=0;n<NREP;n++){
            int row = wn*(BN/2) + n*16 + fr;
            bh[n] = *reinterpret_cast<const bf16x8*>(&Bhs[row*KPAD + fg*8]);
            bl[n] = *reinterpret_cast<const bf16x8*>(&Bls[row*KPAD + fg*8]);
        }
#pragma unroll
        for (int m=0;m<MREP;m++){
            int row = wm*(BM/2) + m*16 + fr;
            bf16x8 ah = *reinterpret_cast<const bf16x8*>(&Ahs[row*KPAD + fg*8]);
            bf16x8 al = *reinterpret_cast<const bf16x8*>(&Als[row*KPAD + fg*8]);
#pragma unroll
            for (int n=0;n<NREP;n++){
                acc[m][n] = __builtin_amdgcn_mfma_f32_16x16x32_bf16(al, bh[n], acc[m][n],0,0,0);
                acc[m][n] = __builtin_amdgcn_mfma_f32_16x16x32_bf16(ah, bl[n], acc[m][n],0,0,0);
                acc[m][n] = __builtin_amdgcn_mfma_f32_16x16x32_bf16(ah, bh[n], acc[m][n],0,0,0);
            }
        }
        __syncthreads();
    }

    // epilogue: row=m0+wm*BM/2+m*16+fg*4+q, col=n0+wn*BN/2+n*16+fr
#pragma unroll
    for (int m=0;m<MREP;m++)
#pragma unroll
      for (int n=0;n<NREP;n++)
#pragma unroll
        for (int q=0;q<4;q++){
            int row = m0 + wm*(BM/2) + m*16 + fg*4 + q;
            int col = n0 + wn*(BN/2) + n*16 + fr;
            float v = acc[m][n][q];
            if (EPI==0) {
                C[(long)row*ldc + col] = v;
            } else if (EPI==1) {
                short h = f2bf(v);
                Ch[(long)row*ldc + col] = h;
                Cl[(long)row*ldc + col] = f2bf(v - bf2f(h));
            } else {
                C[((long)blockIdx.z*NROWS + row)*ldc + col] = v;
            }
        }
}

// ============================================================================
// split-K partial reduce: dbc = sum over 8 slices (float4 per thread)
// ============================================================================
__global__ __launch_bounds__(256) void reduce_dbc(
    const float* __restrict__ part, float* __restrict__ dbc)
{
    long i = ((long)blockIdx.x*256 + threadIdx.x)*4;
    float4 a = *reinterpret_cast<const float4*>(&part[i]);
#pragma unroll
    for (int s=1;s<8;s++){
        float4 b = *reinterpret_cast<const float4*>(&part[(long)s*(NROWS*64) + i]);
        a.x+=b.x; a.y+=b.y; a.z+=b.z; a.w+=b.w;
    }
    *reinterpret_cast<float4*>(&dbc[i]) = a;
}

// ============================================================================
// causal depthwise conv (k=4) + bias + silu; writes split bf16 ONLY (uh/ul)
// ============================================================================
__global__ __launch_bounds__(256) void conv_silu_k(
    const float* __restrict__ xz, const float* __restrict__ cw,
    const float* __restrict__ cb,
    short* __restrict__ uh, short* __restrict__ ul)
{
    int idx = blockIdx.x*256 + threadIdx.x;
    int d4  = idx & (DINNER/4 - 1);
    int row = idx >> 8;
    int t   = row & (LSEQ-1);

    float4 cbv = *reinterpret_cast<const float4*>(&cb[d4*4]);
    float acc[4] = {cbv.x, cbv.y, cbv.z, cbv.w};
    float4 cw0 = *reinterpret_cast<const float4*>(&cw[d4*16 + 0]);
    float4 cw1 = *reinterpret_cast<const float4*>(&cw[d4*16 + 4]);
    float4 cw2 = *reinterpret_cast<const float4*>(&cw[d4*16 + 8]);
    float4 cw3 = *reinterpret_cast<const float4*>(&cw[d4*16 +12]);
    const float* pw[4] = {&cw0.x, &cw1.x, &cw2.x, &cw3.x};

#pragma unroll
    for (int j=0;j<DCONV;j++){
        int tt = t - (DCONV-1) + j;
        if (tt < 0) continue;
        float4 xv = *reinterpret_cast<const float4*>(&xz[(long)(row-(DCONV-1)+j)*2*DINNER + d4*4]);
        acc[0] = fmaf(xv.x, pw[0][j], acc[0]);
        acc[1] = fmaf(xv.y, pw[1][j], acc[1]);
        acc[2] = fmaf(xv.z, pw[2][j], acc[2]);
        acc[3] = fmaf(xv.w, pw[3][j], acc[3]);
    }
    float o[4];
    o[0] = acc[0]*sigmoid_(acc[0]);
    o[1] = acc[1]*sigmoid_(acc[1]);
    o[2] = acc[2]*sigmoid_(acc[2]);
    o[3] = acc[3]*sigmoid_(acc[3]);
    long base = (long)row*DINNER + d4*4;
    shortx4 h, l;
    h.x=f2bf(o[0]); l.x=f2bf(o[0]-bf2f(h.x));
    h.y=f2bf(o[1]); l.y=f2bf(o[1]-bf2f(h.y));
    h.z=f2bf(o[2]); l.z=f2bf(o[2]-bf2f(h.z));
    h.w=f2bf(o[3]); l.w=f2bf(o[3]-bf2f(h.w));
    *reinterpret_cast<shortx4*>(&uh[base]) = h;
    *reinterpret_cast<shortx4*>(&ul[base]) = l;
}

// ============================================================================
// Chunked selective scan with fused delta. u is reconstructed from split bf16
// (u = hi + lo, exact to ~2^-18 relative).
// ============================================================================
#define DTP 36

__global__ __launch_bounds__(256) void scan_phaseA(
    const short* __restrict__ uh, const short* __restrict__ ul,
    const float* __restrict__ dbc,
    const float* __restrict__ Alog, const float* __restrict__ Wdt,
    const float* __restrict__ bdt,
    float* __restrict__ hst, float* __restrict__ sd)
{
    __shared__ float Bsh[CHUNK*DSTATE];
    __shared__ float Dtsh[CHUNK*DTP];
    int bx = blockIdx.x;
    int dblk = bx & 3;
    int c    = (bx>>2) & (NCHUNK-1);
    int b    = bx >> 7;
    int d    = dblk*256 + threadIdx.x;

    {
        int i = threadIdx.x;
        int tr = i >> 3, c4 = (i & 7)*4;
        float4 dv = *reinterpret_cast<const float4*>(&dbc[(long)(b*LSEQ + c*CHUNK + tr)*64 + c4]);
        *reinterpret_cast<float4*>(&Dtsh[tr*DTP + c4]) = dv;
        for (int j = i; j < CHUNK*DSTATE; j += 256) {
            int r = j >> 4, s = j & 15;
            Bsh[j] = dbc[(long)(b*LSEQ + c*CHUNK + r)*64 + DTRANK + s];
        }
    }
    __syncthreads();

    float wdt[DTRANK];
#pragma unroll
    for (int q=0;q<DTRANK;q+=4)
        *reinterpret_cast<float4*>(&wdt[q]) = *reinterpret_cast<const float4*>(&Wdt[(long)d*DTRANK + q]);
    float bias = bdt[d];

    float As[DSTATE];
#pragma unroll
    for (int s=0;s<DSTATE;s++) As[s] = -__expf(Alog[d*DSTATE+s]);
    float h[DSTATE];
#pragma unroll
    for (int s=0;s<DSTATE;s++) h[s]=0.f;
    float sumd = 0.f;

    long baseU = (long)(b*LSEQ + c*CHUNK)*DINNER + d;
    for (int tt=0; tt<CHUNK; ++tt) {
        float v = bias;
#pragma unroll
        for (int r=0;r<DTRANK;r++) v = fmaf(Dtsh[tt*DTP + r], wdt[r], v);
        float dt = softplus_(v);
        long ui = baseU + (long)tt*DINNER;
        float ut = bf2f(uh[ui]) + bf2f(ul[ui]);
        sumd += dt;
        float du = dt*ut;
#pragma unroll
        for (int s=0;s<DSTATE;s++)
            h[s] = fmaf(__expf(As[s]*dt), h[s], du*Bsh[tt*DSTATE+s]);
    }
    long ho = ((long)((b*NCHUNK + c)*DINNER) + d)*DSTATE;
#pragma unroll
    for (int s=0;s<DSTATE;s+=4)
        *reinterpret_cast<float4*>(&hst[ho+s]) = make_float4(h[s],h[s+1],h[s+2],h[s+3]);
    sd[(b*NCHUNK+c)*DINNER + d] = sumd;
}

__global__ __launch_bounds__(256) void scan_phaseB(
    const float* __restrict__ Alog, const float* __restrict__ sd,
    float* __restrict__ hst)
{
    int flat = blockIdx.x*256 + threadIdx.x;
    int s = flat & 15;
    int d = (flat >> 4) & (DINNER-1);
    int b = flat >> 14;
    float As = -__expf(Alog[d*DSTATE+s]);
    float H = 0.f;
    for (int c=0; c<NCHUNK; ++c) {
        long o = ((long)((b*NCHUNK+c)*DINNER)+d)*DSTATE + s;
        float hl  = hst[o];
        float sdc = sd[(b*NCHUNK+c)*DINNER + d];
        hst[o] = H;
        H = fmaf(__expf(As*sdc), H, hl);
    }
}

// uyh/uyl: read as u (split), overwritten in place with gated y (split).
// Strictly per-thread read-then-write at the same index — no cross-thread alias.
__global__ __launch_bounds__(256) void scan_phaseC(
    const float* __restrict__ xz,
    short* uyh, short* uyl,
    const float* __restrict__ dbc, const float* __restrict__ Alog,
    const float* __restrict__ Wdt, const float* __restrict__ bdt,
    const float* __restrict__ hst, const float* __restrict__ Dsk)
{
    __shared__ float Bsh[CHUNK*DSTATE];
    __shared__ float Csh[CHUNK*DSTATE];
    __shared__ float Dtsh[CHUNK*DTP];
    int bx = blockIdx.x;
    int dblk = bx & 3;
    int c    = (bx>>2) & (NCHUNK-1);
    int b    = bx >> 7;
    int d    = dblk*256 + threadIdx.x;

    {
        int i = threadIdx.x;
        int tr = i >> 3, c4 = (i & 7)*4;
        float4 dv = *reinterpret_cast<const float4*>(&dbc[(long)(b*LSEQ + c*CHUNK + tr)*64 + c4]);
        *reinterpret_cast<float4*>(&Dtsh[tr*DTP + c4]) = dv;
        for (int j = i; j < CHUNK*DSTATE; j += 256) {
            int r = j >> 4, s = j & 15;
            long ro = (long)(b*LSEQ + c*CHUNK + r)*64;
            Bsh[j] = dbc[ro + DTRANK + s];
            Csh[j] = dbc[ro + DTRANK + DSTATE + s];
        }
    }
    __syncthreads();

    float wdt[DTRANK];
#pragma unroll
    for (int q=0;q<DTRANK;q+=4)
        *reinterpret_cast<float4*>(&wdt[q]) = *reinterpret_cast<const float4*>(&Wdt[(long)d*DTRANK + q]);
    float bias = bdt[d];

    float As[DSTATE];
#pragma unroll
    for (int s=0;s<DSTATE;s++) As[s] = -__expf(Alog[d*DSTATE+s]);
    float h[DSTATE];
    long ho = ((long)((b*NCHUNK + c)*DINNER) + d)*DSTATE;
#pragma unroll
    for (int s=0;s<DSTATE;s+=4){
        float4 hv = *reinterpret_cast<const float4*>(&hst[ho+s]);
        h[s]=hv.x; h[s+1]=hv.y; h[s+2]=hv.z; h[s+3]=hv.w;
    }
    float Dd = Dsk[d];

    long baseU = (long)(b*LSEQ + c*CHUNK)*DINNER + d;
    long baseZ = (long)(b*LSEQ + c*CHUNK)*2*DINNER + DINNER + d;
    for (int tt=0; tt<CHUNK; ++tt) {
        float v = bias;
#pragma unroll
        for (int r=0;r<DTRANK;r++) v = fmaf(Dtsh[tt*DTP + r], wdt[r], v);
        float dt = softplus_(v);
        long ui = baseU + (long)tt*DINNER;
        float ut = bf2f(uyh[ui]) + bf2f(uyl[ui]);
        float du = dt*ut;
        float y = 0.f;
#pragma unroll
        for (int s=0;s<DSTATE;s++){
            h[s] = fmaf(__expf(As[s]*dt), h[s], du*Bsh[tt*DSTATE+s]);
            y = fmaf(h[s], Csh[tt*DSTATE+s], y);
        }
        y = fmaf(ut, Dd, y);
        float zv = xz[baseZ + (long)tt*2*DINNER];
        y *= zv * sigmoid_(zv);
        short hh = f2bf(y);
        uyh[ui] = hh;
        uyl[ui] = f2bf(y - bf2f(hh));
    }
}

// ============================================================================
extern "C" void kernel_launch(void* const* d_in, const int* in_sizes, int n_in,
                              void* d_out, int out_size, void* d_ws, size_t ws_size,
                              hipStream_t stream)
{
    const float* x_in = (const float*)d_in[0];
    const float* Wi   = (const float*)d_in[1];
    const float* cw   = (const float*)d_in[2];
    const float* cb   = (const float*)d_in[3];
    const float* Wx   = (const float*)d_in[4];
    const float* Wdt  = (const float*)d_in[5];
    const float* bdt  = (const float*)d_in[6];
    const float* Alog = (const float*)d_in[7];
    const float* Dsk  = (const float*)d_in[8];
    const float* Wo   = (const float*)d_in[9];
    float* out = (float*)d_out;

    // workspace layout (~121 MB; ws = 256 MiB per harness fill size).
    // Overlays: partials == hst ; uh/ul == yh/yl (per-thread in-place in scanC).
    float* ws   = (float*)d_ws;
    float* xz   = ws;                        // 8388608 f
    float* dbc  = xz  + 8388608;             // 262144 f
    float* hst  = dbc + 262144;              // 2097152 f (= 8 x 262144 partials)
    float* sd   = hst + 2097152;             // 131072 f
    short* sp   = (short*)(sd + 131072);
    short* srch = sp;                        // 2097152 s (4096x512)
    short* srcl = srch + 2097152;
    short* wsp  = srcl + 2097152;            // 8 * WSTRIDE shorts (all layers)
    short* yh   = wsp  + NLAYER*WSTRIDE;     // 4194304 s (4096x1024), = uh
    short* yl   = yh   + 4194304;            //                        = ul

    // one-time: split layer-0 input + ALL layers' weights
    split_k<<<NROWS*DMODEL/1024, 256, 0, stream>>>(x_in, srch, srcl);
    split_w_all<<<NLAYER*1600, 256, 0, stream>>>(Wi, Wo, Wx, wsp);

    for (int l=0; l<NLAYER; ++l) {
        const float* cw_l  = cw  + (long)l*DINNER*DCONV;
        const float* cb_l  = cb  + (long)l*DINNER;
        const float* Wdt_l = Wdt + (long)l*DINNER*DTRANK;
        const float* bdt_l = bdt + (long)l*DINNER;
        const float* Al_l  = Alog+ (long)l*DINNER*DSTATE;
        const float* Dsk_l = Dsk + (long)l*DINNER;
        short* lw  = wsp + (long)l*WSTRIDE;
        short* wih = lw,            *wil = lw+1048576;
        short* woh = lw+2097152,    *wol = lw+2621440;
        short* wxh = lw+3145728,    *wxl = lw+3211264;

        // 1) xz = src @ Wi^T  (4096 x 2048, K=512)  128x128 tiles -> 512 blocks
        gemm_bs_nt<128,128,0,false,2><<<dim3(2*DINNER/128, NROWS/128), 256, 0, stream>>>(
            srch, srcl, DMODEL, wih, wil, DMODEL, xz, 2*DINNER, nullptr, nullptr, DMODEL, DMODEL);

        // 2) u = silu(causal_dwconv(xin) + cb) -> split bf16 only (uh/ul = yh/yl)
        conv_silu_k<<<NROWS*(DINNER/4)/256, 256, 0, stream>>>(xz, cw_l, cb_l, yh, yl);

        // 3) dbc partials = u @ Wx^T (4096x64, K=1024) MFMA split-K=8 -> 256 blocks
        gemm_bs_nt<128,64,2,true,4><<<dim3(1, NROWS/128, 8), 256, 0, stream>>>(
            yh, yl, DINNER, wxh, wxl, DINNER, hst, 64, nullptr, nullptr, DINNER, DINNER/8);
        reduce_dbc<<<NROWS*64/1024, 256, 0, stream>>>(hst, dbc);

        // 4-6) chunked scan with fused delta; phaseC overwrites uh/ul with y
        scan_phaseA<<<B_SZ*NCHUNK*(DINNER/256), 256, 0, stream>>>(
            yh, yl, dbc, Al_l, Wdt_l, bdt_l, hst, sd);
        scan_phaseB<<<B_SZ*DINNER*DSTATE/256, 256, 0, stream>>>(Al_l, sd, hst);
        scan_phaseC<<<B_SZ*NCHUNK*(DINNER/256), 256, 0, stream>>>(
            xz, yh, yl, dbc, Al_l, Wdt_l, bdt_l, hst, Dsk_l);

        // 7) out = y @ Wo^T  (4096 x 512, K=1024)  64x64 tiles -> 512 blocks
        if (l == NLAYER-1) {
            gemm_bs_nt<64,64,0,false,4><<<dim3(DMODEL/64, NROWS/64), 256, 0, stream>>>(
                yh, yl, DINNER, woh, wol, DINNER, out, DMODEL, nullptr, nullptr, DINNER, DINNER);
        } else {
            gemm_bs_nt<64,64,1,false,4><<<dim3(DMODEL/64, NROWS/64), 256, 0, stream>>>(
                yh, yl, DINNER, woh, wol, DINNER, nullptr, DMODEL, srch, srcl, DINNER, DINNER);
        }
    }
}